// Round 12
// baseline (3914.840 us; speedup 1.0000x reference)
//
#include <hip/hip_runtime.h>
#include <math.h>

#define NN 262144
#define EE 2097152
#define FIN 14
#define LW 128
#define TW 15

typedef unsigned short ushort_t;
typedef unsigned int uint_t;
typedef __attribute__((ext_vector_type(8))) short bf16x8v;
typedef __attribute__((ext_vector_type(4))) float f32x4v;

static __device__ __forceinline__ float sigmoidf_(float v) { return 1.0f / (1.0f + expf(-v)); }

static __device__ __forceinline__ float bf2f(unsigned short u) {
  union { unsigned int i; float f; } v; v.i = ((unsigned int)u) << 16; return v.f;
}
static __device__ __forceinline__ unsigned short f2bf(float f) {
  union { float f; unsigned int i; } v; v.f = f;
  unsigned int r = v.i + 0x7FFF + ((v.i >> 16) & 1);  // RNE
  return (unsigned short)(r >> 16);
}
static __device__ __forceinline__ unsigned int pack2(float a, float b) {
  return ((unsigned int)f2bf(b) << 16) | (unsigned int)f2bf(a);
}
static __device__ __forceinline__ void addrow8(float* acc, uint4 u) {
  acc[0] += bf2f((unsigned short)(u.x & 0xFFFF)); acc[1] += bf2f((unsigned short)(u.x >> 16));
  acc[2] += bf2f((unsigned short)(u.y & 0xFFFF)); acc[3] += bf2f((unsigned short)(u.y >> 16));
  acc[4] += bf2f((unsigned short)(u.z & 0xFFFF)); acc[5] += bf2f((unsigned short)(u.z >> 16));
  acc[6] += bf2f((unsigned short)(u.w & 0xFFFF)); acc[7] += bf2f((unsigned short)(u.w >> 16));
}
static __device__ __forceinline__ void addrow4(float* acc, uint2 u) {
  acc[0] += bf2f((unsigned short)(u.x & 0xFFFF)); acc[1] += bf2f((unsigned short)(u.x >> 16));
  acc[2] += bf2f((unsigned short)(u.y & 0xFFFF)); acc[3] += bf2f((unsigned short)(u.y >> 16));
}
static __device__ __forceinline__ int swz9(int a) { return a ^ (((a >> 9) & 7) << 4); }

// ================= device bodies =================

// ---- TAG Horner hop body (2 threads/node); Ws/Ws2 are shared float[256] ----
template<int MODE>
static __device__ __forceinline__ void tag_body(
    int blk, int t, float* Ws, float* Ws2,
    const ushort_t* __restrict__ T, const float* __restrict__ W, int win,
    const ushort_t* __restrict__ w_in, ushort_t* __restrict__ w_out,
    const float* __restrict__ bias,
    const float* __restrict__ W2, int win2, ushort_t* __restrict__ w_next2,
    const int* __restrict__ row_start, const int* __restrict__ csr_src,
    const float* __restrict__ dinv) {
  { int rr = t >> 4, c = t & 15;
    Ws[t] = (rr < win && c < TW) ? W[rr * TW + c] : 0.0f;
    if (MODE == 3) Ws2[t] = (rr < win2 && c < TW) ? W2[rr * TW + c] : 0.0f; }
  __syncthreads();
  int gi = blk * 256 + t;
  int i = gi >> 1, half = gi & 1;
  float di = dinv[i];
  uint4 t0 = *(const uint4*)(T + (size_t)i * 16);
  uint4 t1 = *(const uint4*)(T + (size_t)i * 16 + 8);
  float acc[8];
  #pragma unroll
  for (int c = 0; c < 8; ++c) acc[c] = 0.0f;

  if (MODE != 0) {
    const ushort_t* wbase = w_in + half * 8;
    int e0 = row_start[i], e1 = row_start[i + 1];
    int e = e0;
    if ((e & 1) && e < e1) {
      addrow8(acc, *(const uint4*)(wbase + (size_t)csr_src[e] * 16));
      ++e;
    }
    for (; e + 8 <= e1; e += 8) {
      uint2 p0 = *(const uint2*)(csr_src + e);
      uint2 p1 = *(const uint2*)(csr_src + e + 2);
      uint2 p2 = *(const uint2*)(csr_src + e + 4);
      uint2 p3 = *(const uint2*)(csr_src + e + 6);
      int id[8] = {(int)p0.x, (int)p0.y, (int)p1.x, (int)p1.y,
                   (int)p2.x, (int)p2.y, (int)p3.x, (int)p3.y};
      uint4 u[8];
      #pragma unroll
      for (int j = 0; j < 8; ++j) u[j] = *(const uint4*)(wbase + (size_t)id[j] * 16);
      #pragma unroll
      for (int j = 0; j < 8; ++j) addrow8(acc, u[j]);
    }
    for (; e + 2 <= e1; e += 2) {
      uint2 p = *(const uint2*)(csr_src + e);
      uint4 u0 = *(const uint4*)(wbase + (size_t)p.x * 16);
      uint4 u1 = *(const uint4*)(wbase + (size_t)p.y * 16);
      addrow8(acc, u0); addrow8(acc, u1);
    }
    if (e < e1) addrow8(acc, *(const uint4*)(wbase + (size_t)csr_src[e] * 16));
    #pragma unroll
    for (int c = 0; c < 8; ++c) acc[c] *= di;
  }

  float tv[16];
  tv[0]=bf2f((unsigned short)(t0.x&0xFFFF)); tv[1]=bf2f((unsigned short)(t0.x>>16));
  tv[2]=bf2f((unsigned short)(t0.y&0xFFFF)); tv[3]=bf2f((unsigned short)(t0.y>>16));
  tv[4]=bf2f((unsigned short)(t0.z&0xFFFF)); tv[5]=bf2f((unsigned short)(t0.z>>16));
  tv[6]=bf2f((unsigned short)(t0.w&0xFFFF)); tv[7]=bf2f((unsigned short)(t0.w>>16));
  tv[8]=bf2f((unsigned short)(t1.x&0xFFFF)); tv[9]=bf2f((unsigned short)(t1.x>>16));
  tv[10]=bf2f((unsigned short)(t1.y&0xFFFF)); tv[11]=bf2f((unsigned short)(t1.y>>16));
  tv[12]=bf2f((unsigned short)(t1.z&0xFFFF)); tv[13]=bf2f((unsigned short)(t1.z>>16));
  tv[14]=bf2f((unsigned short)(t1.w&0xFFFF)); tv[15]=bf2f((unsigned short)(t1.w>>16));
  #pragma unroll
  for (int f = 0; f < 16; ++f) {
    float tf = tv[f];
    const float4* wr = (const float4*)&Ws[f * 16 + half * 8];
    float4 w0 = wr[0], w1 = wr[1];
    acc[0]+=tf*w0.x; acc[1]+=tf*w0.y; acc[2]+=tf*w0.z; acc[3]+=tf*w0.w;
    acc[4]+=tf*w1.x; acc[5]+=tf*w1.y; acc[6]+=tf*w1.z; acc[7]+=tf*w1.w;
  }

  if (MODE >= 2) {
    int cbase = half * 8;
    float tn[8];
    #pragma unroll
    for (int c = 0; c < 8; ++c)
      tn[c] = (cbase + c < TW) ? sigmoidf_(acc[c] + bias[cbase + c]) : 0.0f;
    uint4 o = make_uint4(pack2(tn[0],tn[1]), pack2(tn[2],tn[3]),
                         pack2(tn[4],tn[5]), pack2(tn[6],tn[7]));
    *(uint4*)(w_out + (size_t)i * 16 + cbase) = o;
    if (MODE == 3) {
      float to[8];
      #pragma unroll
      for (int c = 0; c < 8; ++c) to[c] = __shfl_xor(tn[c], 1);
      float lo[8], hi[8];
      #pragma unroll
      for (int c = 0; c < 8; ++c) {
        lo[c] = half ? to[c] : tn[c];
        hi[c] = half ? tn[c] : to[c];
      }
      float wn[8];
      #pragma unroll
      for (int c = 0; c < 8; ++c) wn[c] = 0.0f;
      #pragma unroll
      for (int f = 0; f < 8; ++f) {
        float tf = lo[f];
        const float4* wr = (const float4*)&Ws2[f * 16 + cbase];
        float4 w0 = wr[0], w1 = wr[1];
        wn[0]+=tf*w0.x; wn[1]+=tf*w0.y; wn[2]+=tf*w0.z; wn[3]+=tf*w0.w;
        wn[4]+=tf*w1.x; wn[5]+=tf*w1.y; wn[6]+=tf*w1.z; wn[7]+=tf*w1.w;
      }
      #pragma unroll
      for (int f = 0; f < 8; ++f) {
        float tf = hi[f];
        const float4* wr = (const float4*)&Ws2[(f + 8) * 16 + cbase];
        float4 w0 = wr[0], w1 = wr[1];
        wn[0]+=tf*w0.x; wn[1]+=tf*w0.y; wn[2]+=tf*w0.z; wn[3]+=tf*w0.w;
        wn[4]+=tf*w1.x; wn[5]+=tf*w1.y; wn[6]+=tf*w1.z; wn[7]+=tf*w1.w;
      }
      uint4 o2 = make_uint4(pack2(di*wn[0],di*wn[1]), pack2(di*wn[2],di*wn[3]),
                            pack2(di*wn[4],di*wn[5]), pack2(di*wn[6],di*wn[7]));
      *(uint4*)(w_next2 + (size_t)i * 16 + cbase) = o2;
    }
  } else {
    uint4 o = make_uint4(pack2(di*acc[0],di*acc[1]), pack2(di*acc[2],di*acc[3]),
                         pack2(di*acc[4],di*acc[5]), pack2(di*acc[6],di*acc[7]));
    *(uint4*)(w_out + (size_t)i * 16 + half * 8) = o;
  }
}

// ---- width-128 mean aggregation body (4 nodes/block, 2 rows/wave, 8B/lane) ----
static __device__ __forceinline__ void prop128_body(
    int blk, int t,
    const ushort_t* __restrict__ h, ushort_t* __restrict__ out,
    const int* __restrict__ row_start, const int* __restrict__ csr_src,
    const float* __restrict__ inv_deg) {
  int g = blk * 4 + (t >> 6);
  int lane = t & 63;
  int sub = lane >> 5;
  int li = lane & 31;
  int s0 = row_start[g], s1 = row_start[g + 1];
  float acc[4];
  #pragma unroll
  for (int c = 0; c < 4; ++c) acc[c] = 0.0f;
  const ushort_t* hb = h + li * 4;
  int e = s0;
  for (; e + 16 <= s1; e += 16) {
    int id[8];
    #pragma unroll
    for (int j = 0; j < 8; ++j) id[j] = csr_src[e + 2 * j + sub];
    uint2 u[8];
    #pragma unroll
    for (int j = 0; j < 8; ++j) u[j] = *(const uint2*)(hb + (size_t)id[j] * LW);
    #pragma unroll
    for (int j = 0; j < 8; ++j) addrow4(acc, u[j]);
  }
  for (; e + 8 <= s1; e += 8) {
    int id[4];
    #pragma unroll
    for (int j = 0; j < 4; ++j) id[j] = csr_src[e + 2 * j + sub];
    uint2 u[4];
    #pragma unroll
    for (int j = 0; j < 4; ++j) u[j] = *(const uint2*)(hb + (size_t)id[j] * LW);
    #pragma unroll
    for (int j = 0; j < 4; ++j) addrow4(acc, u[j]);
  }
  for (; e + 2 <= s1; e += 2) {
    int id = csr_src[e + sub];
    addrow4(acc, *(const uint2*)(hb + (size_t)id * LW));
  }
  if (e < s1 && sub == 0) {
    int id = csr_src[e];
    addrow4(acc, *(const uint2*)(hb + (size_t)id * LW));
  }
  #pragma unroll
  for (int c = 0; c < 4; ++c) acc[c] += __shfl_xor(acc[c], 32);
  float idg = inv_deg[g];
  if (sub == 0) {
    uint2 o = make_uint2(pack2(acc[0] * idg, acc[1] * idg), pack2(acc[2] * idg, acc[3] * idg));
    *(uint2*)(out + (size_t)g * LW + li * 4) = o;
  }
}

// ---- width-16 mean aggregation body (2 threads/node) ----
static __device__ __forceinline__ void prop16b_body(
    int blk, int t,
    const ushort_t* __restrict__ h, ushort_t* __restrict__ xc,
    const int* __restrict__ row_start, const int* __restrict__ csr_src,
    const float* __restrict__ inv_deg) {
  int gi = blk * 256 + t;
  int i = gi >> 1, half = gi & 1;
  float acc[8];
  #pragma unroll
  for (int c = 0; c < 8; ++c) acc[c] = 0.0f;
  const ushort_t* wbase = h + half * 8;
  int e0 = row_start[i], e1 = row_start[i + 1];
  int e = e0;
  if ((e & 1) && e < e1) {
    addrow8(acc, *(const uint4*)(wbase + (size_t)csr_src[e] * 16));
    ++e;
  }
  for (; e + 8 <= e1; e += 8) {
    uint2 p0 = *(const uint2*)(csr_src + e);
    uint2 p1 = *(const uint2*)(csr_src + e + 2);
    uint2 p2 = *(const uint2*)(csr_src + e + 4);
    uint2 p3 = *(const uint2*)(csr_src + e + 6);
    int id[8] = {(int)p0.x, (int)p0.y, (int)p1.x, (int)p1.y,
                 (int)p2.x, (int)p2.y, (int)p3.x, (int)p3.y};
    uint4 u[8];
    #pragma unroll
    for (int j = 0; j < 8; ++j) u[j] = *(const uint4*)(wbase + (size_t)id[j] * 16);
    #pragma unroll
    for (int j = 0; j < 8; ++j) addrow8(acc, u[j]);
  }
  for (; e + 2 <= e1; e += 2) {
    uint2 p = *(const uint2*)(csr_src + e);
    uint4 u0 = *(const uint4*)(wbase + (size_t)p.x * 16);
    uint4 u1 = *(const uint4*)(wbase + (size_t)p.y * 16);
    addrow8(acc, u0); addrow8(acc, u1);
  }
  if (e < e1) addrow8(acc, *(const uint4*)(wbase + (size_t)csr_src[e] * 16));
  float idg = inv_deg[i];
  uint4 o = make_uint4(pack2(acc[0]*idg, acc[1]*idg), pack2(acc[2]*idg, acc[3]*idg),
                       pack2(acc[4]*idg, acc[5]*idg), pack2(acc[6]*idg, acc[7]*idg));
  *(uint4*)(xc + (size_t)i * 32 + half * 8) = o;
}

// ---- SAGE layer-6 bodies ----
static __device__ __forceinline__ void wide_to1_body(
    int blk, int t,
    const ushort_t* __restrict__ H, const float* __restrict__ Wl3,
    const float* __restrict__ Wr3, float* __restrict__ g_l, float* __restrict__ g_r) {
  int wave = (blk * 256 + t) >> 6;
  int lane = t & 63;
  unsigned int u = *(const unsigned int*)(H + (size_t)wave * LW + 2 * lane);
  float h0 = bf2f((unsigned short)(u & 0xFFFF));
  float h1 = bf2f((unsigned short)(u >> 16));
  float al = h0 * Wl3[2 * lane] + h1 * Wl3[2 * lane + 1];
  float ar = h0 * Wr3[2 * lane] + h1 * Wr3[2 * lane + 1];
  #pragma unroll
  for (int off = 32; off; off >>= 1) {
    al += __shfl_xor(al, off);
    ar += __shfl_xor(ar, off);
  }
  if (lane == 0) { g_l[wave] = al; g_r[wave] = ar; }
}

static __device__ __forceinline__ void sage_final_body(
    int blk, int t,
    const float* __restrict__ g_l, const float* __restrict__ g_r,
    const float* __restrict__ b3, const int* __restrict__ row_start,
    const int* __restrict__ csr_src, const float* __restrict__ inv_deg,
    float* __restrict__ x1) {
  int i = blk * 256 + t;
  int e0 = row_start[i], e1 = row_start[i + 1];
  float s = 0.0f;
  int e = e0;
  if ((e & 1) && e < e1) { s += g_l[csr_src[e]]; ++e; }
  for (; e + 8 <= e1; e += 8) {
    uint2 p0 = *(const uint2*)(csr_src + e);
    uint2 p1 = *(const uint2*)(csr_src + e + 2);
    uint2 p2 = *(const uint2*)(csr_src + e + 4);
    uint2 p3 = *(const uint2*)(csr_src + e + 6);
    float w0 = g_l[p0.x], w1 = g_l[p0.y], w2 = g_l[p1.x], w3 = g_l[p1.y];
    float w4 = g_l[p2.x], w5 = g_l[p2.y], w6 = g_l[p3.x], w7 = g_l[p3.y];
    s += ((w0 + w1) + (w2 + w3)) + ((w4 + w5) + (w6 + w7));
  }
  for (; e < e1; ++e) s += g_l[csr_src[e]];
  float v = s * inv_deg[i] + g_r[i] + b3[0];
  x1[i] = fmaxf(v, 0.0f);
}

// ================= kernels =================

__global__ void k_selprobe(const unsigned char* __restrict__ selb, int* __restrict__ flag) {
  __shared__ int cnt;
  if (threadIdx.x == 0) cnt = 0;
  __syncthreads();
  int c = 0;
  for (int i = threadIdx.x; i < 4096; i += 256) c += (selb[i] != 0) ? 1 : 0;
  atomicAdd(&cnt, c);
  __syncthreads();
  if (threadIdx.x == 0) *flag = (cnt > 3000) ? 1 : 0;
}

__global__ void k_deg(const int* __restrict__ ei, int* __restrict__ deg, int* __restrict__ pos) {
  int e = blockIdx.x * 256 + threadIdx.x;
  if (e < EE) pos[e] = atomicAdd(&deg[ei[EE + e]], 1);
}

__global__ void k_scan_partial(const int* __restrict__ deg, int* __restrict__ btot) {
  __shared__ int sd[256];
  int t = threadIdx.x, b = blockIdx.x;
  int i0 = b * 1024 + t * 4;
  int s = deg[i0] + deg[i0 + 1] + deg[i0 + 2] + deg[i0 + 3];
  sd[t] = s; __syncthreads();
  for (int off = 1; off < 256; off <<= 1) {
    int x = (t >= off) ? sd[t - off] : 0;
    __syncthreads(); sd[t] += x; __syncthreads();
  }
  if (t == 255) btot[b] = sd[255];
}

__global__ void k_scan_block(const int* __restrict__ btot, int* __restrict__ bbase, int* __restrict__ row_start) {
  __shared__ int sd[256];
  int t = threadIdx.x;
  int v = btot[t];
  sd[t] = v; __syncthreads();
  for (int off = 1; off < 256; off <<= 1) {
    int x = (t >= off) ? sd[t - off] : 0;
    __syncthreads(); sd[t] += x; __syncthreads();
  }
  bbase[t] = sd[t] - v;
  if (t == 255) row_start[NN] = sd[255];
}

__global__ void k_scan_final(const int* __restrict__ deg, const int* __restrict__ bbase,
                             int* __restrict__ row_start, float* __restrict__ inv_deg,
                             float* __restrict__ dinv) {
  __shared__ int sd[256];
  int t = threadIdx.x, b = blockIdx.x;
  int i0 = b * 1024 + t * 4;
  int d0 = deg[i0], d1 = deg[i0 + 1], d2 = deg[i0 + 2], d3 = deg[i0 + 3];
  int s = d0 + d1 + d2 + d3;
  sd[t] = s; __syncthreads();
  for (int off = 1; off < 256; off <<= 1) {
    int x = (t >= off) ? sd[t - off] : 0;
    __syncthreads(); sd[t] += x; __syncthreads();
  }
  int base = bbase[b] + sd[t] - s;
  row_start[i0]     = base;
  row_start[i0 + 1] = base + d0;
  row_start[i0 + 2] = base + d0 + d1;
  row_start[i0 + 3] = base + d0 + d1 + d2;
  int dd[4] = {d0, d1, d2, d3};
  for (int j = 0; j < 4; ++j) {
    float df = (float)dd[j];
    inv_deg[i0 + j] = 1.0f / fmaxf(df, 1.0f);
    dinv[i0 + j] = (dd[j] > 0) ? rsqrtf(fmaxf(df, 1.0f)) : 0.0f;
  }
}

__global__ void k_fill(const int* __restrict__ ei, const int* __restrict__ row_start,
                       const int* __restrict__ pos, int* __restrict__ csr_src) {
  int e = blockIdx.x * 256 + threadIdx.x;
  if (e >= EE) return;
  int s = ei[e], d = ei[EE + e];
  csr_src[row_start[d] + pos[e]] = s;
}

__global__ void k_pad_x(const float* __restrict__ x, ushort_t* __restrict__ xpb,
                        ushort_t* __restrict__ xc) {
  int idx = blockIdx.x * 256 + threadIdx.x;
  int i = idx >> 4, lane = idx & 15;
  float v = (lane < FIN) ? x[(size_t)i * FIN + lane] : 0.0f;
  ushort_t b = f2bf(v);
  xpb[idx] = b;
  xc[(size_t)i * 32 + 16 + lane] = b;
}

__global__ void k_convW1(const float* __restrict__ Wl1, const float* __restrict__ Wr1,
                         ushort_t* __restrict__ Wc) {
  int idx = blockIdx.x * 256 + threadIdx.x;
  int n = idx >> 5, k = idx & 31;
  float v = 0.0f;
  if (k < FIN) v = Wl1[k * 128 + n];
  else if (k >= 16 && k < 16 + FIN) v = Wr1[(k - 16) * 128 + n];
  Wc[idx] = f2bf(v);
}

__global__ __launch_bounds__(256) void k_gemm_small_mfma(
    const ushort_t* __restrict__ xc, const ushort_t* __restrict__ Wc,
    const float* __restrict__ bias, ushort_t* __restrict__ out) {
  int tid = threadIdx.x;
  int wave = tid >> 6, lane = tid & 63;
  int row0 = blockIdx.x * 64 + wave * 16;
  int r = lane & 15, kg = lane >> 4;
  bf16x8v a = *(const bf16x8v*)(xc + (size_t)(row0 + r) * 32 + kg * 8);
  f32x4v acc[8];
  #pragma unroll
  for (int nt = 0; nt < 8; ++nt) {
    acc[nt] = (f32x4v){0.f, 0.f, 0.f, 0.f};
    bf16x8v b = *(const bf16x8v*)(Wc + (size_t)(nt * 16 + r) * 32 + kg * 8);
    acc[nt] = __builtin_amdgcn_mfma_f32_16x16x32_bf16(a, b, acc[nt], 0, 0, 0);
  }
  #pragma unroll
  for (int nt = 0; nt < 8; ++nt) {
    #pragma unroll
    for (int j = 0; j < 4; ++j) {
      float v = sigmoidf_(acc[nt][j] + bias[nt * 16 + r]);
      out[(size_t)(row0 + kg * 4 + j) * LW + nt * 16 + r] = f2bf(v);
    }
  }
}

__global__ void k_convW(const float* __restrict__ Wl, const float* __restrict__ Wr,
                        ushort_t* __restrict__ Wt) {
  int idx = blockIdx.x * 256 + threadIdx.x;
  int n = idx >> 8, k = idx & 255;
  float v = (k < 128) ? Wl[k * 128 + n] : Wr[(k - 128) * 128 + n];
  Wt[idx] = f2bf(v);
}

__global__ __launch_bounds__(512) void k_gemm128_mfma(
    const ushort_t* __restrict__ A1, const ushort_t* __restrict__ A2,
    const ushort_t* __restrict__ Wt, const float* __restrict__ bias,
    ushort_t* __restrict__ out) {
  __shared__ ushort_t Bs[32768];
  int tid = threadIdx.x;
  {
    const uint4* src = (const uint4*)Wt;
    #pragma unroll
    for (int j = 0; j < 8; ++j) {
      int idx16 = tid * 8 + j;
      uint4 v = src[idx16];
      *(uint4*)((char*)Bs + swz9(idx16 * 16)) = v;
    }
  }
  __syncthreads();
  int wave = tid >> 6, lane = tid & 63;
  int row0 = blockIdx.x * 256 + wave * 32;
  int r = lane & 15, kg = lane >> 4;
  f32x4v acc[2][8];
  #pragma unroll
  for (int mt = 0; mt < 2; ++mt)
    #pragma unroll
    for (int nt = 0; nt < 8; ++nt) acc[mt][nt] = (f32x4v){0.f, 0.f, 0.f, 0.f};
  #pragma unroll
  for (int ks = 0; ks < 8; ++ks) {
    bf16x8v a[2];
    #pragma unroll
    for (int mt = 0; mt < 2; ++mt) {
      const ushort_t* asrc = (ks < 4)
          ? (A1 + (size_t)(row0 + mt * 16 + r) * LW + ks * 32 + kg * 8)
          : (A2 + (size_t)(row0 + mt * 16 + r) * LW + (ks - 4) * 32 + kg * 8);
      a[mt] = *(const bf16x8v*)asrc;
    }
    #pragma unroll
    for (int nt = 0; nt < 8; ++nt) {
      int baddr = (nt * 16 + r) * 512 + ks * 64 + kg * 16;
      bf16x8v b = *(const bf16x8v*)((char*)Bs + swz9(baddr));
      acc[0][nt] = __builtin_amdgcn_mfma_f32_16x16x32_bf16(a[0], b, acc[0][nt], 0, 0, 0);
      acc[1][nt] = __builtin_amdgcn_mfma_f32_16x16x32_bf16(a[1], b, acc[1][nt], 0, 0, 0);
    }
  }
  #pragma unroll
  for (int mt = 0; mt < 2; ++mt) {
    #pragma unroll
    for (int nt = 0; nt < 8; ++nt) {
      #pragma unroll
      for (int j = 0; j < 4; ++j) {
        float v = sigmoidf_(acc[mt][nt][j] + bias[nt * 16 + r]);
        out[(size_t)(row0 + mt * 16 + kg * 4 + j) * LW + nt * 16 + r] = f2bf(v);
      }
    }
  }
}

// ---- standalone TAG hop ----
template<int MODE>
__global__ __launch_bounds__(256) void k_tag_hh(
    const ushort_t* T, const float* W, int win,
    const ushort_t* w_in, ushort_t* w_out, const float* bias,
    const float* W2, int win2, ushort_t* w_next2,
    const int* row_start, const int* csr_src, const float* dinv) {
  __shared__ float Ws[256];
  __shared__ float Ws2[256];
  tag_body<MODE>(blockIdx.x, threadIdx.x, Ws, Ws2, T, W, win, w_in, w_out, bias,
                 W2, win2, w_next2, row_start, csr_src, dinv);
}

// ---- combined: prop16b (even blocks) ∥ tag hop (odd blocks) ----
template<int MODE>
__global__ __launch_bounds__(256) void k_c_p16_tag(
    const ushort_t* h, ushort_t* xc, const float* inv_deg,
    const ushort_t* T, const float* W, int win,
    const ushort_t* w_in, ushort_t* w_out,
    const int* row_start, const int* csr_src, const float* dinv) {
  __shared__ float Ws[256];
  int bi = blockIdx.x;
  if ((bi & 1) == 0) prop16b_body(bi >> 1, threadIdx.x, h, xc, row_start, csr_src, inv_deg);
  else tag_body<MODE>(bi >> 1, threadIdx.x, Ws, nullptr, T, W, win, w_in, w_out, nullptr,
                      nullptr, 0, nullptr, row_start, csr_src, dinv);
}

// ---- combined: prop128 ∥ tag hop, 33-interleave (grid 67584 = 33*2048) ----
template<int MODE>
__global__ __launch_bounds__(256) void k_c_p128_tag(
    const ushort_t* h, ushort_t* out, const float* inv_deg,
    const ushort_t* T, const float* W, int win,
    const ushort_t* w_in, ushort_t* w_out,
    const int* row_start, const int* csr_src, const float* dinv) {
  __shared__ float Ws[256];
  int bi = blockIdx.x;
  int q = bi / 33;
  if (bi - q * 33 == 0)
    tag_body<MODE>(q, threadIdx.x, Ws, nullptr, T, W, win, w_in, w_out, nullptr,
                   nullptr, 0, nullptr, row_start, csr_src, dinv);
  else
    prop128_body(bi - q - 1, threadIdx.x, h, out, row_start, csr_src, inv_deg);
}

// ---- combined: wide_to1 ∥ tag hop, 33-interleave ----
template<int MODE>
__global__ __launch_bounds__(256) void k_c_wide_tag(
    const ushort_t* H, const float* Wl3, const float* Wr3,
    float* g_l, float* g_r,
    const ushort_t* T, const float* W, int win,
    const ushort_t* w_in, ushort_t* w_out,
    const int* row_start, const int* csr_src, const float* dinv) {
  __shared__ float Ws[256];
  int bi = blockIdx.x;
  int q = bi / 33;
  if (bi - q * 33 == 0)
    tag_body<MODE>(q, threadIdx.x, Ws, nullptr, T, W, win, w_in, w_out, nullptr,
                   nullptr, 0, nullptr, row_start, csr_src, dinv);
  else
    wide_to1_body(bi - q - 1, threadIdx.x, H, Wl3, Wr3, g_l, g_r);
}

// ---- combined: sage_final ∥ tag hop, grid 3072: bi%3==0 -> final, else tag ----
template<int MODE>
__global__ __launch_bounds__(256) void k_c_final_tag(
    const float* g_l, const float* g_r, const float* b3, const float* inv_deg,
    float* x1,
    const ushort_t* T, const float* W, int win,
    const ushort_t* w_in, ushort_t* w_out,
    const int* row_start, const int* csr_src, const float* dinv) {
  __shared__ float Ws[256];
  int bi = blockIdx.x;
  int q = bi / 3;
  if (bi - q * 3 == 0)
    sage_final_body(q, threadIdx.x, g_l, g_r, b3, row_start, csr_src, inv_deg, x1);
  else
    tag_body<MODE>(bi - q - 1, threadIdx.x, Ws, nullptr, T, W, win, w_in, w_out, nullptr,
                   nullptr, 0, nullptr, row_start, csr_src, dinv);
}

// ---- TAG layer 6 ----
__global__ void k_tag_g(const ushort_t* __restrict__ T, const float* __restrict__ Wt3,
                        const float* __restrict__ dinv, float* __restrict__ gT,
                        float* __restrict__ w15) {
  __shared__ float Ws[16 * TW];
  int t = threadIdx.x;
  if (t < 16 * TW) Ws[t] = Wt3[t];
  __syncthreads();
  int i = blockIdx.x * 256 + t;
  const ushort_t* tr = T + (size_t)i * 16;
  float row[TW];
  #pragma unroll
  for (int f = 0; f < TW; ++f) row[f] = bf2f(tr[f]);
  #pragma unroll
  for (int k = 0; k < 16; ++k) {
    float a = 0.0f;
    #pragma unroll
    for (int f = 0; f < TW; ++f) a += row[f] * Ws[k * TW + f];
    if (k < 15) gT[(size_t)k * NN + i] = a;
    else        w15[i] = dinv[i] * a;
  }
}

__global__ void k_horner(const float* __restrict__ gk, const float* __restrict__ w_in,
                         float* __restrict__ w_out,
                         const int* __restrict__ row_start, const int* __restrict__ csr_src,
                         const float* __restrict__ dinv) {
  int i = blockIdx.x * 256 + threadIdx.x;
  int e0 = row_start[i], e1 = row_start[i + 1];
  float gs = 0.0f;
  int e = e0;
  if ((e & 1) && e < e1) { gs += w_in[csr_src[e]]; ++e; }
  for (; e + 8 <= e1; e += 8) {
    uint2 p0 = *(const uint2*)(csr_src + e);
    uint2 p1 = *(const uint2*)(csr_src + e + 2);
    uint2 p2 = *(const uint2*)(csr_src + e + 4);
    uint2 p3 = *(const uint2*)(csr_src + e + 6);
    float w0 = w_in[p0.x], w1 = w_in[p0.y], w2 = w_in[p1.x], w3 = w_in[p1.y];
    float w4 = w_in[p2.x], w5 = w_in[p2.y], w6 = w_in[p3.x], w7 = w_in[p3.y];
    gs += ((w0 + w1) + (w2 + w3)) + ((w4 + w5) + (w6 + w7));
  }
  for (; e < e1; ++e) gs += w_in[csr_src[e]];
  float s = gk[i] + dinv[i] * gs;
  w_out[i] = dinv[i] * s;
}

__global__ void k_horner_fin(const float* __restrict__ g0, const float* __restrict__ w_in,
                             const float* __restrict__ x1, const int* __restrict__ y,
                             const unsigned char* __restrict__ selb, const int* __restrict__ selflag,
                             const float* __restrict__ Wlin, const float* __restrict__ blin,
                             const float* __restrict__ bt3,
                             const int* __restrict__ row_start, const int* __restrict__ csr_src,
                             const float* __restrict__ dinv, float* __restrict__ out) {
  int i = blockIdx.x * 256 + threadIdx.x;
  int e0 = row_start[i], e1 = row_start[i + 1];
  float gs = 0.0f;
  int e = e0;
  if ((e & 1) && e < e1) { gs += w_in[csr_src[e]]; ++e; }
  for (; e + 8 <= e1; e += 8) {
    uint2 p0 = *(const uint2*)(csr_src + e);
    uint2 p1 = *(const uint2*)(csr_src + e + 2);
    uint2 p2 = *(const uint2*)(csr_src + e + 4);
    uint2 p3 = *(const uint2*)(csr_src + e + 6);
    float w0 = w_in[p0.x], w1 = w_in[p0.y], w2 = w_in[p1.x], w3 = w_in[p1.y];
    float w4 = w_in[p2.x], w5 = w_in[p2.y], w6 = w_in[p3.x], w7 = w_in[p3.y];
    gs += ((w0 + w1) + (w2 + w3)) + ((w4 + w5) + (w6 + w7));
  }
  for (; e < e1; ++e) gs += w_in[csr_src[e]];
  float s = g0[i] + dinv[i] * gs;
  float x3 = fmaxf(s + bt3[0], 0.0f);
  float v = fmaxf(x1[i] * Wlin[0] + x3 * Wlin[1] + blin[0], 0.0f);
  bool selv = (*selflag) ? (selb[i] != 0) : (((const int*)selb)[i] != 0);
  bool z = selv && (y[i] == 0);
  out[i] = z ? 0.0f : v;
}

extern "C" void kernel_launch(void* const* d_in, const int* in_sizes, int n_in,
                              void* d_out, int out_size, void* d_ws, size_t ws_size,
                              hipStream_t stream) {
  const float* x    = (const float*)d_in[0];
  const int*   ei   = (const int*)d_in[1];
  const int*   y    = (const int*)d_in[2];
  const unsigned char* sel = (const unsigned char*)d_in[3];
  const float* Wl1  = (const float*)d_in[4];
  const float* Wr1  = (const float*)d_in[5];
  const float* b1   = (const float*)d_in[6];
  const float* Wl2  = (const float*)d_in[7];
  const float* Wr2  = (const float*)d_in[8];
  const float* b2   = (const float*)d_in[9];
  const float* Wl3  = (const float*)d_in[10];
  const float* Wr3  = (const float*)d_in[11];
  const float* b3   = (const float*)d_in[12];
  const float* Wt1  = (const float*)d_in[13];
  const float* bt1  = (const float*)d_in[14];
  const float* Wt2  = (const float*)d_in[15];
  const float* bt2  = (const float*)d_in[16];
  const float* Wt3  = (const float*)d_in[17];
  const float* bt3  = (const float*)d_in[18];
  const float* Wlin = (const float*)d_in[19];
  const float* blin = (const float*)d_in[20];

  const size_t MB = 1 << 20;
  unsigned char* w8 = (unsigned char*)d_ws;
  int*   deg       = (int*)(w8 + 0 * MB);
  int*   row_start = (int*)(w8 + 2 * MB);
  float* inv_deg   = (float*)(w8 + 4 * MB);
  float* dinv      = (float*)(w8 + 5 * MB);
  float* x1        = (float*)(w8 + 6 * MB);
  float* g_l       = (float*)(w8 + 7 * MB);
  float* g_r       = (float*)(w8 + 8 * MB);
  int*   btot      = (int*)(w8 + 9 * MB);
  int*   bbase     = (int*)(w8 + 9 * MB + 4096);
  int*   selflag   = (int*)(w8 + 9 * MB + 8192);
  float* w6a       = (float*)(w8 + 11 * MB);
  float* w6b       = (float*)(w8 + 12 * MB);
  ushort_t* Wtc    = (ushort_t*)(w8 + 14 * MB);
  ushort_t* Wc1    = (ushort_t*)(w8 + 15 * MB);
  int*   csr_src   = (int*)(w8 + 16 * MB);
  int*   pos       = (int*)(w8 + 24 * MB);
  ushort_t* xpb    = (ushort_t*)(w8 + 40 * MB);
  ushort_t* H      = (ushort_t*)(w8 + 48 * MB);
  ushort_t* AGG    = (ushort_t*)(w8 + 112 * MB);
  ushort_t* xc     = (ushort_t*)(w8 + 112 * MB);  // overlay (dead before prop128)
  ushort_t* T0  = (ushort_t*)(w8 + 112 * MB);
  ushort_t* T1  = (ushort_t*)(w8 + 120 * MB);
  ushort_t* wA  = (ushort_t*)(w8 + 128 * MB);
  ushort_t* wB  = (ushort_t*)(w8 + 136 * MB);
  float* gT     = (float*)(w8 + 144 * MB);

  const size_t FT = (size_t)FIN * TW;
  const size_t TT = (size_t)TW * TW;
  const int TG = NN * 2 / 256;        // 2048
  const int PG = NN / 4;              // 65536
  const int CG33 = PG + TG;           // 67584 = 33*2048

  // ---- sel probe + preprocessing ----
  k_selprobe<<<1, 256, 0, stream>>>(sel, selflag);
  hipMemsetAsync(deg, 0, MB, stream);
  k_deg<<<EE / 256, 256, 0, stream>>>(ei, deg, pos);
  k_scan_partial<<<256, 256, 0, stream>>>(deg, btot);
  k_scan_block<<<1, 256, 0, stream>>>(btot, bbase, row_start);
  k_scan_final<<<256, 256, 0, stream>>>(deg, bbase, row_start, inv_deg, dinv);
  k_fill<<<EE / 256, 256, 0, stream>>>(ei, row_start, pos, csr_src);
  k_pad_x<<<NN * 16 / 256, 256, 0, stream>>>(x, xpb, xc);
  k_convW<<<128, 256, 0, stream>>>(Wl2, Wr2, Wtc);
  k_convW1<<<16, 256, 0, stream>>>(Wl1, Wr1, Wc1);

  ushort_t* wi = wA; ushort_t* wo = wB;

  // ---- SAGE ∥ TAG layer-1 hops ----
  // P1: prop16b ∥ hop(mode0, k=15)
  k_c_p16_tag<0><<<2 * TG, 256, 0, stream>>>(xpb, xc, inv_deg,
                                             xpb, Wt1 + 15 * FT, FIN, nullptr, wi,
                                             row_start, csr_src, dinv);
  k_gemm_small_mfma<<<NN / 64, 256, 0, stream>>>(xc, Wc1, b1, H);
  // P2..P5: prop128(l) ∥ hop(mode1, k=14..11)
  for (int l = 0; l < 4; ++l) {
    int k = 14 - l;
    k_c_p128_tag<1><<<CG33, 256, 0, stream>>>(H, AGG, inv_deg,
                                              xpb, Wt1 + (size_t)k * FT, FIN, wi, wo,
                                              row_start, csr_src, dinv);
    { ushort_t* tmp = wi; wi = wo; wo = tmp; }
    k_gemm128_mfma<<<NN / 256, 512, 0, stream>>>(AGG, H, Wtc, b2, H);
  }
  // P6: wide_to1 ∥ hop(mode1, k=10)
  k_c_wide_tag<1><<<CG33, 256, 0, stream>>>(H, Wl3, Wr3, g_l, g_r,
                                            xpb, Wt1 + 10 * FT, FIN, wi, wo,
                                            row_start, csr_src, dinv);
  { ushort_t* tmp = wi; wi = wo; wo = tmp; }
  // P7: sage_final ∥ hop(mode1, k=9)
  k_c_final_tag<1><<<3 * (NN / 256), 256, 0, stream>>>(g_l, g_r, b3, inv_deg, x1,
                                                       xpb, Wt1 + 9 * FT, FIN, wi, wo,
                                                       row_start, csr_src, dinv);
  { ushort_t* tmp = wi; wi = wo; wo = tmp; }

  // ---- remaining TAG layer-1 hops (k=8..1) + transition ----
  for (int k = 8; k >= 1; --k) {
    k_tag_hh<1><<<TG, 256, 0, stream>>>(xpb, Wt1 + (size_t)k * FT, FIN, wi, wo, nullptr,
                                        nullptr, 0, nullptr, row_start, csr_src, dinv);
    ushort_t* tmp = wi; wi = wo; wo = tmp;
  }
  k_tag_hh<3><<<TG, 256, 0, stream>>>(xpb, Wt1, FIN, wi, T0, bt1,
                                      Wt2 + 15 * TT, TW, wo, row_start, csr_src, dinv);
  { ushort_t* tmp = wi; wi = wo; wo = tmp; }

  // ---- TAG layers 2-5 ----
  ushort_t* tin = T0; ushort_t* tout = T1;
  for (int l = 0; l < 4; ++l) {
    for (int k = 14; k >= 1; --k) {
      k_tag_hh<1><<<TG, 256, 0, stream>>>(tin, Wt2 + (size_t)k * TT, TW, wi, wo, nullptr,
                                          nullptr, 0, nullptr, row_start, csr_src, dinv);
      ushort_t* tmp = wi; wi = wo; wo = tmp;
    }
    if (l < 3) {
      k_tag_hh<3><<<TG, 256, 0, stream>>>(tin, Wt2, TW, wi, tout, bt2,
                                          Wt2 + 15 * TT, TW, wo, row_start, csr_src, dinv);
      ushort_t* tmp = wi; wi = wo; wo = tmp;
    } else {
      k_tag_hh<2><<<TG, 256, 0, stream>>>(tin, Wt2, TW, wi, tout, bt2,
                                          nullptr, 0, nullptr, row_start, csr_src, dinv);
    }
    ushort_t* tmp = tin; tin = tout; tout = tmp;
  }

  // ---- TAG layer 6 ----
  k_tag_g<<<NN / 256, 256, 0, stream>>>(tin, Wt3, dinv, gT, w6a);
  float* fwi = w6a; float* fwo = w6b;
  for (int k = 14; k >= 1; --k) {
    k_horner<<<NN / 256, 256, 0, stream>>>(gT + (size_t)k * NN, fwi, fwo,
                                           row_start, csr_src, dinv);
    float* tmp = fwi; fwi = fwo; fwo = tmp;
  }
  k_horner_fin<<<NN / 256, 256, 0, stream>>>(gT, fwi, x1, y, sel, selflag, Wlin, blin, bt3,
                                             row_start, csr_src, dinv, (float*)d_out);
}

// Round 13
// 3565.005 us; speedup vs baseline: 1.0981x; 1.0981x over previous
//
#include <hip/hip_runtime.h>
#include <math.h>

#define NN 262144
#define EE 2097152
#define FIN 14
#define LW 128
#define TW 15

typedef unsigned short ushort_t;
typedef unsigned int uint_t;
typedef __attribute__((ext_vector_type(8))) short bf16x8v;
typedef __attribute__((ext_vector_type(4))) float f32x4v;

static __device__ __forceinline__ float sigmoidf_(float v) { return 1.0f / (1.0f + expf(-v)); }

static __device__ __forceinline__ float bf2f(unsigned short u) {
  union { unsigned int i; float f; } v; v.i = ((unsigned int)u) << 16; return v.f;
}
static __device__ __forceinline__ unsigned short f2bf(float f) {
  union { float f; unsigned int i; } v; v.f = f;
  unsigned int r = v.i + 0x7FFF + ((v.i >> 16) & 1);  // RNE
  return (unsigned short)(r >> 16);
}
static __device__ __forceinline__ unsigned int pack2(float a, float b) {
  return ((unsigned int)f2bf(b) << 16) | (unsigned int)f2bf(a);
}
// add 8 bf16 (one uint4) into acc[0..7]
static __device__ __forceinline__ void addrow8(float* acc, uint4 u) {
  acc[0] += bf2f((unsigned short)(u.x & 0xFFFF)); acc[1] += bf2f((unsigned short)(u.x >> 16));
  acc[2] += bf2f((unsigned short)(u.y & 0xFFFF)); acc[3] += bf2f((unsigned short)(u.y >> 16));
  acc[4] += bf2f((unsigned short)(u.z & 0xFFFF)); acc[5] += bf2f((unsigned short)(u.z >> 16));
  acc[6] += bf2f((unsigned short)(u.w & 0xFFFF)); acc[7] += bf2f((unsigned short)(u.w >> 16));
}
// add 4 bf16 (one uint2) into acc[0..3]
static __device__ __forceinline__ void addrow4(float* acc, uint2 u) {
  acc[0] += bf2f((unsigned short)(u.x & 0xFFFF)); acc[1] += bf2f((unsigned short)(u.x >> 16));
  acc[2] += bf2f((unsigned short)(u.y & 0xFFFF)); acc[3] += bf2f((unsigned short)(u.y >> 16));
}
// LDS XOR swizzle for 512B-stride rows
static __device__ __forceinline__ int swz9(int a) { return a ^ (((a >> 9) & 7) << 4); }

// ---------------- sel dtype probe ----------------
__global__ void k_selprobe(const unsigned char* __restrict__ selb, int* __restrict__ flag) {
  __shared__ int cnt;
  if (threadIdx.x == 0) cnt = 0;
  __syncthreads();
  int c = 0;
  for (int i = threadIdx.x; i < 4096; i += 256) c += (selb[i] != 0) ? 1 : 0;
  atomicAdd(&cnt, c);
  __syncthreads();
  if (threadIdx.x == 0) *flag = (cnt > 3000) ? 1 : 0;  // 1 = byte-bool, 0 = int32
}

// ---------------- degree + per-edge position ----------------
__global__ void k_deg(const int* __restrict__ ei, int* __restrict__ deg, int* __restrict__ pos) {
  int e = blockIdx.x * 256 + threadIdx.x;
  if (e < EE) pos[e] = atomicAdd(&deg[ei[EE + e]], 1);
}

// ---------------- scan ----------------
__global__ void k_scan_partial(const int* __restrict__ deg, int* __restrict__ btot) {
  __shared__ int sd[256];
  int t = threadIdx.x, b = blockIdx.x;
  int i0 = b * 1024 + t * 4;
  int s = deg[i0] + deg[i0 + 1] + deg[i0 + 2] + deg[i0 + 3];
  sd[t] = s; __syncthreads();
  for (int off = 1; off < 256; off <<= 1) {
    int x = (t >= off) ? sd[t - off] : 0;
    __syncthreads(); sd[t] += x; __syncthreads();
  }
  if (t == 255) btot[b] = sd[255];
}

__global__ void k_scan_block(const int* __restrict__ btot, int* __restrict__ bbase, int* __restrict__ row_start) {
  __shared__ int sd[256];
  int t = threadIdx.x;
  int v = btot[t];
  sd[t] = v; __syncthreads();
  for (int off = 1; off < 256; off <<= 1) {
    int x = (t >= off) ? sd[t - off] : 0;
    __syncthreads(); sd[t] += x; __syncthreads();
  }
  bbase[t] = sd[t] - v;
  if (t == 255) row_start[NN] = sd[255];
}

__global__ void k_scan_final(const int* __restrict__ deg, const int* __restrict__ bbase,
                             int* __restrict__ row_start, float* __restrict__ inv_deg,
                             float* __restrict__ dinv) {
  __shared__ int sd[256];
  int t = threadIdx.x, b = blockIdx.x;
  int i0 = b * 1024 + t * 4;
  int d0 = deg[i0], d1 = deg[i0 + 1], d2 = deg[i0 + 2], d3 = deg[i0 + 3];
  int s = d0 + d1 + d2 + d3;
  sd[t] = s; __syncthreads();
  for (int off = 1; off < 256; off <<= 1) {
    int x = (t >= off) ? sd[t - off] : 0;
    __syncthreads(); sd[t] += x; __syncthreads();
  }
  int base = bbase[b] + sd[t] - s;
  row_start[i0]     = base;
  row_start[i0 + 1] = base + d0;
  row_start[i0 + 2] = base + d0 + d1;
  row_start[i0 + 3] = base + d0 + d1 + d2;
  int dd[4] = {d0, d1, d2, d3};
  for (int j = 0; j < 4; ++j) {
    float df = (float)dd[j];
    inv_deg[i0 + j] = 1.0f / fmaxf(df, 1.0f);
    dinv[i0 + j] = (dd[j] > 0) ? rsqrtf(fmaxf(df, 1.0f)) : 0.0f;
  }
}

// ---------------- CSR fill (atomic-free: uses precomputed pos) ----------------
__global__ void k_fill(const int* __restrict__ ei, const int* __restrict__ row_start,
                       const int* __restrict__ pos, int* __restrict__ csr_src) {
  int e = blockIdx.x * 256 + threadIdx.x;
  if (e >= EE) return;
  int s = ei[e], d = ei[EE + e];
  csr_src[row_start[d] + pos[e]] = s;
}

// ---------------- pad x: bf16 xpb + xc[:,16:32] ----------------
__global__ void k_pad_x(const float* __restrict__ x, ushort_t* __restrict__ xpb,
                        ushort_t* __restrict__ xc) {
  int idx = blockIdx.x * 256 + threadIdx.x;   // over NN*16
  int i = idx >> 4, lane = idx & 15;
  float v = (lane < FIN) ? x[(size_t)i * FIN + lane] : 0.0f;
  ushort_t b = f2bf(v);
  xpb[idx] = b;
  xc[(size_t)i * 32 + 16 + lane] = b;
}

// ---------------- width-16 mean aggregation, 2 threads/node -> xc[:,0:16] ----------------
__global__ __launch_bounds__(256) void k_prop16b(
    const ushort_t* __restrict__ h, ushort_t* __restrict__ xc,
    const int* __restrict__ row_start, const int* __restrict__ csr_src,
    const float* __restrict__ inv_deg) {
  int gi = blockIdx.x * 256 + threadIdx.x;
  int i = gi >> 1, half = gi & 1;
  float acc[8];
  #pragma unroll
  for (int c = 0; c < 8; ++c) acc[c] = 0.0f;
  const ushort_t* wbase = h + half * 8;
  int e0 = row_start[i], e1 = row_start[i + 1];
  int e = e0;
  if ((e & 1) && e < e1) {
    addrow8(acc, *(const uint4*)(wbase + (size_t)csr_src[e] * 16));
    ++e;
  }
  for (; e + 8 <= e1; e += 8) {
    uint2 p0 = *(const uint2*)(csr_src + e);
    uint2 p1 = *(const uint2*)(csr_src + e + 2);
    uint2 p2 = *(const uint2*)(csr_src + e + 4);
    uint2 p3 = *(const uint2*)(csr_src + e + 6);
    int id[8] = {(int)p0.x, (int)p0.y, (int)p1.x, (int)p1.y,
                 (int)p2.x, (int)p2.y, (int)p3.x, (int)p3.y};
    uint4 u[8];
    #pragma unroll
    for (int j = 0; j < 8; ++j) u[j] = *(const uint4*)(wbase + (size_t)id[j] * 16);
    #pragma unroll
    for (int j = 0; j < 8; ++j) addrow8(acc, u[j]);
  }
  for (; e + 2 <= e1; e += 2) {
    uint2 p = *(const uint2*)(csr_src + e);
    uint4 u0 = *(const uint4*)(wbase + (size_t)p.x * 16);
    uint4 u1 = *(const uint4*)(wbase + (size_t)p.y * 16);
    addrow8(acc, u0); addrow8(acc, u1);
  }
  if (e < e1) addrow8(acc, *(const uint4*)(wbase + (size_t)csr_src[e] * 16));
  float idg = inv_deg[i];
  uint4 o = make_uint4(pack2(acc[0]*idg, acc[1]*idg), pack2(acc[2]*idg, acc[3]*idg),
                       pack2(acc[4]*idg, acc[5]*idg), pack2(acc[6]*idg, acc[7]*idg));
  *(uint4*)(xc + (size_t)i * 32 + half * 8) = o;
}

// ---------------- layer-1 weight concat ----------------
__global__ void k_convW1(const float* __restrict__ Wl1, const float* __restrict__ Wr1,
                         ushort_t* __restrict__ Wc) {
  int idx = blockIdx.x * 256 + threadIdx.x;   // 4096
  int n = idx >> 5, k = idx & 31;
  float v = 0.0f;
  if (k < FIN) v = Wl1[k * 128 + n];
  else if (k >= 16 && k < 16 + FIN) v = Wr1[(k - 16) * 128 + n];
  Wc[idx] = f2bf(v);
}

// ---------------- layer-1 MFMA GEMM ----------------
__global__ __launch_bounds__(256) void k_gemm_small_mfma(
    const ushort_t* __restrict__ xc, const ushort_t* __restrict__ Wc,
    const float* __restrict__ bias, ushort_t* __restrict__ out) {
  int tid = threadIdx.x;
  int wave = tid >> 6, lane = tid & 63;
  int row0 = blockIdx.x * 64 + wave * 16;
  int r = lane & 15, kg = lane >> 4;
  bf16x8v a = *(const bf16x8v*)(xc + (size_t)(row0 + r) * 32 + kg * 8);
  f32x4v acc[8];
  #pragma unroll
  for (int nt = 0; nt < 8; ++nt) {
    acc[nt] = (f32x4v){0.f, 0.f, 0.f, 0.f};
    bf16x8v b = *(const bf16x8v*)(Wc + (size_t)(nt * 16 + r) * 32 + kg * 8);
    acc[nt] = __builtin_amdgcn_mfma_f32_16x16x32_bf16(a, b, acc[nt], 0, 0, 0);
  }
  #pragma unroll
  for (int nt = 0; nt < 8; ++nt) {
    #pragma unroll
    for (int j = 0; j < 4; ++j) {
      float v = sigmoidf_(acc[nt][j] + bias[nt * 16 + r]);
      out[(size_t)(row0 + kg * 4 + j) * LW + nt * 16 + r] = f2bf(v);
    }
  }
}

// ---------------- width-128 mean aggregation: 2 rows/wave, 8B/lane, x4 pairs ----------------
__global__ __launch_bounds__(256) void k_prop128(
    const ushort_t* __restrict__ h, ushort_t* __restrict__ out,
    const int* __restrict__ row_start, const int* __restrict__ csr_src,
    const float* __restrict__ inv_deg) {
  int t = threadIdx.x;
  int g = blockIdx.x * 4 + (t >> 6);
  int lane = t & 63;
  int sub = lane >> 5;       // 0: even edge, 1: odd edge
  int li = lane & 31;        // covers elements 4*li .. 4*li+3
  int s0 = row_start[g], s1 = row_start[g + 1];
  float acc[4];
  #pragma unroll
  for (int c = 0; c < 4; ++c) acc[c] = 0.0f;
  const ushort_t* hb = h + li * 4;
  int e = s0;
  for (; e + 8 <= s1; e += 8) {
    int id[4];
    #pragma unroll
    for (int j = 0; j < 4; ++j) id[j] = csr_src[e + 2 * j + sub];
    uint2 u[4];
    #pragma unroll
    for (int j = 0; j < 4; ++j) u[j] = *(const uint2*)(hb + (size_t)id[j] * LW);
    #pragma unroll
    for (int j = 0; j < 4; ++j) addrow4(acc, u[j]);
  }
  for (; e + 2 <= s1; e += 2) {
    int id = csr_src[e + sub];
    addrow4(acc, *(const uint2*)(hb + (size_t)id * LW));
  }
  if (e < s1 && sub == 0) {
    int id = csr_src[e];
    addrow4(acc, *(const uint2*)(hb + (size_t)id * LW));
  }
  #pragma unroll
  for (int c = 0; c < 4; ++c) acc[c] += __shfl_xor(acc[c], 32);
  float idg = inv_deg[g];
  if (sub == 0) {
    uint2 o = make_uint2(pack2(acc[0] * idg, acc[1] * idg), pack2(acc[2] * idg, acc[3] * idg));
    *(uint2*)(out + (size_t)g * LW + li * 4) = o;
  }
}

// ---------------- weight conversion ----------------
__global__ void k_convW(const float* __restrict__ Wl, const float* __restrict__ Wr,
                        ushort_t* __restrict__ Wt) {
  int idx = blockIdx.x * 256 + threadIdx.x;   // over 128*256
  int n = idx >> 8, k = idx & 255;
  float v = (k < 128) ? Wl[k * 128 + n] : Wr[(k - 128) * 128 + n];
  Wt[idx] = f2bf(v);
}

// ---------------- MFMA SAGE GEMM: B staged in LDS (swizzled), 256 rows/block, 8 waves ----
__global__ __launch_bounds__(512) void k_gemm128_mfma(
    const ushort_t* __restrict__ A1, const ushort_t* __restrict__ A2,
    const ushort_t* __restrict__ Wt,   // [128][256] bf16 = 64 KB
    const float* __restrict__ bias, ushort_t* __restrict__ out) {
  __shared__ ushort_t Bs[32768];       // 64 KB, XOR-swizzled
  int tid = threadIdx.x;
  {
    const uint4* src = (const uint4*)Wt;
    #pragma unroll
    for (int j = 0; j < 8; ++j) {
      int idx16 = tid * 8 + j;
      uint4 v = src[idx16];
      *(uint4*)((char*)Bs + swz9(idx16 * 16)) = v;
    }
  }
  __syncthreads();
  int wave = tid >> 6, lane = tid & 63;
  int row0 = blockIdx.x * 256 + wave * 32;
  int r = lane & 15, kg = lane >> 4;
  f32x4v acc[2][8];
  #pragma unroll
  for (int mt = 0; mt < 2; ++mt)
    #pragma unroll
    for (int nt = 0; nt < 8; ++nt) acc[mt][nt] = (f32x4v){0.f, 0.f, 0.f, 0.f};
  #pragma unroll
  for (int ks = 0; ks < 8; ++ks) {
    bf16x8v a[2];
    #pragma unroll
    for (int mt = 0; mt < 2; ++mt) {
      const ushort_t* asrc = (ks < 4)
          ? (A1 + (size_t)(row0 + mt * 16 + r) * LW + ks * 32 + kg * 8)
          : (A2 + (size_t)(row0 + mt * 16 + r) * LW + (ks - 4) * 32 + kg * 8);
      a[mt] = *(const bf16x8v*)asrc;
    }
    #pragma unroll
    for (int nt = 0; nt < 8; ++nt) {
      int baddr = (nt * 16 + r) * 512 + ks * 64 + kg * 16;
      bf16x8v b = *(const bf16x8v*)((char*)Bs + swz9(baddr));
      acc[0][nt] = __builtin_amdgcn_mfma_f32_16x16x32_bf16(a[0], b, acc[0][nt], 0, 0, 0);
      acc[1][nt] = __builtin_amdgcn_mfma_f32_16x16x32_bf16(a[1], b, acc[1][nt], 0, 0, 0);
    }
  }
  #pragma unroll
  for (int mt = 0; mt < 2; ++mt) {
    #pragma unroll
    for (int nt = 0; nt < 8; ++nt) {
      #pragma unroll
      for (int j = 0; j < 4; ++j) {
        float v = sigmoidf_(acc[mt][nt][j] + bias[nt * 16 + r]);
        out[(size_t)(row0 + mt * 16 + kg * 4 + j) * LW + nt * 16 + r] = f2bf(v);
      }
    }
  }
}

// ---------------- SAGE layer 6 ----------------
__global__ void k_wide_to1(const ushort_t* __restrict__ H, const float* __restrict__ Wl3,
                           const float* __restrict__ Wr3, float* __restrict__ g_l,
                           float* __restrict__ g_r) {
  int wave = (blockIdx.x * 256 + threadIdx.x) >> 6;
  int lane = threadIdx.x & 63;
  unsigned int u = *(const unsigned int*)(H + (size_t)wave * LW + 2 * lane);
  float h0 = bf2f((unsigned short)(u & 0xFFFF));
  float h1 = bf2f((unsigned short)(u >> 16));
  float al = h0 * Wl3[2 * lane] + h1 * Wl3[2 * lane + 1];
  float ar = h0 * Wr3[2 * lane] + h1 * Wr3[2 * lane + 1];
  #pragma unroll
  for (int off = 32; off; off >>= 1) {
    al += __shfl_xor(al, off);
    ar += __shfl_xor(ar, off);
  }
  if (lane == 0) { g_l[wave] = al; g_r[wave] = ar; }
}

__global__ void k_sage_final(const float* __restrict__ g_l, const float* __restrict__ g_r,
                             const float* __restrict__ b3, const int* __restrict__ row_start,
                             const int* __restrict__ csr_src, const float* __restrict__ inv_deg,
                             float* __restrict__ x1) {
  int i = blockIdx.x * 256 + threadIdx.x;
  int e0 = row_start[i], e1 = row_start[i + 1];
  float s = 0.0f;
  int e = e0;
  if ((e & 1) && e < e1) { s += g_l[csr_src[e]]; ++e; }
  for (; e + 8 <= e1; e += 8) {
    uint2 p0 = *(const uint2*)(csr_src + e);
    uint2 p1 = *(const uint2*)(csr_src + e + 2);
    uint2 p2 = *(const uint2*)(csr_src + e + 4);
    uint2 p3 = *(const uint2*)(csr_src + e + 6);
    float w0 = g_l[p0.x], w1 = g_l[p0.y], w2 = g_l[p1.x], w3 = g_l[p1.y];
    float w4 = g_l[p2.x], w5 = g_l[p2.y], w6 = g_l[p3.x], w7 = g_l[p3.y];
    s += ((w0 + w1) + (w2 + w3)) + ((w4 + w5) + (w6 + w7));
  }
  for (; e < e1; ++e) s += g_l[csr_src[e]];
  float v = s * inv_deg[i] + g_r[i] + b3[0];
  x1[i] = fmaxf(v, 0.0f);
}

// ---------------- TAG Horner hop, 2 threads/node, uint2 id loads ----------------
template<int MODE>
__global__ __launch_bounds__(256) void k_tag_hh(
    const ushort_t* __restrict__ T, const float* __restrict__ W, int win,
    const ushort_t* __restrict__ w_in, ushort_t* __restrict__ w_out,
    const float* __restrict__ bias,
    const float* __restrict__ W2, int win2, ushort_t* __restrict__ w_next2,
    const int* __restrict__ row_start, const int* __restrict__ csr_src,
    const float* __restrict__ dinv) {
  __shared__ float Ws[16][16];
  __shared__ float Ws2[16][16];
  int t = threadIdx.x;
  { int rr = t >> 4, c = t & 15;
    Ws[rr][c] = (rr < win && c < TW) ? W[rr * TW + c] : 0.0f;
    if (MODE == 3) Ws2[rr][c] = (rr < win2 && c < TW) ? W2[rr * TW + c] : 0.0f; }
  __syncthreads();
  int gi = blockIdx.x * 256 + t;
  int i = gi >> 1, half = gi & 1;
  float di = dinv[i];
  uint4 t0 = *(const uint4*)(T + (size_t)i * 16);
  uint4 t1 = *(const uint4*)(T + (size_t)i * 16 + 8);
  float acc[8];
  #pragma unroll
  for (int c = 0; c < 8; ++c) acc[c] = 0.0f;

  if (MODE != 0) {
    const ushort_t* wbase = w_in + half * 8;
    int e0 = row_start[i], e1 = row_start[i + 1];
    int e = e0;
    if ((e & 1) && e < e1) {
      addrow8(acc, *(const uint4*)(wbase + (size_t)csr_src[e] * 16));
      ++e;
    }
    for (; e + 8 <= e1; e += 8) {
      uint2 p0 = *(const uint2*)(csr_src + e);
      uint2 p1 = *(const uint2*)(csr_src + e + 2);
      uint2 p2 = *(const uint2*)(csr_src + e + 4);
      uint2 p3 = *(const uint2*)(csr_src + e + 6);
      int id[8] = {(int)p0.x, (int)p0.y, (int)p1.x, (int)p1.y,
                   (int)p2.x, (int)p2.y, (int)p3.x, (int)p3.y};
      uint4 u[8];
      #pragma unroll
      for (int j = 0; j < 8; ++j) u[j] = *(const uint4*)(wbase + (size_t)id[j] * 16);
      #pragma unroll
      for (int j = 0; j < 8; ++j) addrow8(acc, u[j]);
    }
    for (; e + 2 <= e1; e += 2) {
      uint2 p = *(const uint2*)(csr_src + e);
      uint4 u0 = *(const uint4*)(wbase + (size_t)p.x * 16);
      uint4 u1 = *(const uint4*)(wbase + (size_t)p.y * 16);
      addrow8(acc, u0); addrow8(acc, u1);
    }
    if (e < e1) addrow8(acc, *(const uint4*)(wbase + (size_t)csr_src[e] * 16));
    #pragma unroll
    for (int c = 0; c < 8; ++c) acc[c] *= di;
  }

  float tv[16];
  tv[0]=bf2f((unsigned short)(t0.x&0xFFFF)); tv[1]=bf2f((unsigned short)(t0.x>>16));
  tv[2]=bf2f((unsigned short)(t0.y&0xFFFF)); tv[3]=bf2f((unsigned short)(t0.y>>16));
  tv[4]=bf2f((unsigned short)(t0.z&0xFFFF)); tv[5]=bf2f((unsigned short)(t0.z>>16));
  tv[6]=bf2f((unsigned short)(t0.w&0xFFFF)); tv[7]=bf2f((unsigned short)(t0.w>>16));
  tv[8]=bf2f((unsigned short)(t1.x&0xFFFF)); tv[9]=bf2f((unsigned short)(t1.x>>16));
  tv[10]=bf2f((unsigned short)(t1.y&0xFFFF)); tv[11]=bf2f((unsigned short)(t1.y>>16));
  tv[12]=bf2f((unsigned short)(t1.z&0xFFFF)); tv[13]=bf2f((unsigned short)(t1.z>>16));
  tv[14]=bf2f((unsigned short)(t1.w&0xFFFF)); tv[15]=bf2f((unsigned short)(t1.w>>16));
  #pragma unroll
  for (int f = 0; f < 16; ++f) {
    float tf = tv[f];
    const float4* wr = (const float4*)&Ws[f][half * 8];
    float4 w0 = wr[0], w1 = wr[1];
    acc[0]+=tf*w0.x; acc[1]+=tf*w0.y; acc[2]+=tf*w0.z; acc[3]+=tf*w0.w;
    acc[4]+=tf*w1.x; acc[5]+=tf*w1.y; acc[6]+=tf*w1.z; acc[7]+=tf*w1.w;
  }

  if (MODE >= 2) {
    int cbase = half * 8;
    float tn[8];
    #pragma unroll
    for (int c = 0; c < 8; ++c)
      tn[c] = (cbase + c < TW) ? sigmoidf_(acc[c] + bias[cbase + c]) : 0.0f;
    uint4 o = make_uint4(pack2(tn[0],tn[1]), pack2(tn[2],tn[3]),
                         pack2(tn[4],tn[5]), pack2(tn[6],tn[7]));
    *(uint4*)(w_out + (size_t)i * 16 + cbase) = o;
    if (MODE == 3) {
      float to[8];
      #pragma unroll
      for (int c = 0; c < 8; ++c) to[c] = __shfl_xor(tn[c], 1);
      float lo[8], hi[8];
      #pragma unroll
      for (int c = 0; c < 8; ++c) {
        lo[c] = half ? to[c] : tn[c];
        hi[c] = half ? tn[c] : to[c];
      }
      float wn[8];
      #pragma unroll
      for (int c = 0; c < 8; ++c) wn[c] = 0.0f;
      #pragma unroll
      for (int f = 0; f < 8; ++f) {
        float tf = lo[f];
        const float4* wr = (const float4*)&Ws2[f][cbase];
        float4 w0 = wr[0], w1 = wr[1];
        wn[0]+=tf*w0.x; wn[1]+=tf*w0.y; wn[2]+=tf*w0.z; wn[3]+=tf*w0.w;
        wn[4]+=tf*w1.x; wn[5]+=tf*w1.y; wn[6]+=tf*w1.z; wn[7]+=tf*w1.w;
      }
      #pragma unroll
      for (int f = 0; f < 8; ++f) {
        float tf = hi[f];
        const float4* wr = (const float4*)&Ws2[f + 8][cbase];
        float4 w0 = wr[0], w1 = wr[1];
        wn[0]+=tf*w0.x; wn[1]+=tf*w0.y; wn[2]+=tf*w0.z; wn[3]+=tf*w0.w;
        wn[4]+=tf*w1.x; wn[5]+=tf*w1.y; wn[6]+=tf*w1.z; wn[7]+=tf*w1.w;
      }
      uint4 o2 = make_uint4(pack2(di*wn[0],di*wn[1]), pack2(di*wn[2],di*wn[3]),
                            pack2(di*wn[4],di*wn[5]), pack2(di*wn[6],di*wn[7]));
      *(uint4*)(w_next2 + (size_t)i * 16 + cbase) = o2;
    }
  } else {
    uint4 o = make_uint4(pack2(di*acc[0],di*acc[1]), pack2(di*acc[2],di*acc[3]),
                         pack2(di*acc[4],di*acc[5]), pack2(di*acc[6],di*acc[7]));
    *(uint4*)(w_out + (size_t)i * 16 + half * 8) = o;
  }
}

// ---------------- TAG layer 6: gT k=0..14, w15 = dinv*g15 ----------------
__global__ void k_tag_g(const ushort_t* __restrict__ T, const float* __restrict__ Wt3,
                        const float* __restrict__ dinv, float* __restrict__ gT,
                        float* __restrict__ w15) {
  __shared__ float Ws[16 * TW];
  int t = threadIdx.x;
  if (t < 16 * TW) Ws[t] = Wt3[t];
  __syncthreads();
  int i = blockIdx.x * 256 + t;
  const ushort_t* tr = T + (size_t)i * 16;
  float row[TW];
  #pragma unroll
  for (int f = 0; f < TW; ++f) row[f] = bf2f(tr[f]);
  #pragma unroll
  for (int k = 0; k < 16; ++k) {
    float a = 0.0f;
    #pragma unroll
    for (int f = 0; f < TW; ++f) a += row[f] * Ws[k * TW + f];
    if (k < 15) gT[(size_t)k * NN + i] = a;
    else        w15[i] = dinv[i] * a;
  }
}

// ---------------- layer-6 Horner hop, uint2 ids ----------------
__global__ void k_horner(const float* __restrict__ gk, const float* __restrict__ w_in,
                         float* __restrict__ w_out,
                         const int* __restrict__ row_start, const int* __restrict__ csr_src,
                         const float* __restrict__ dinv) {
  int i = blockIdx.x * 256 + threadIdx.x;
  int e0 = row_start[i], e1 = row_start[i + 1];
  float gs = 0.0f;
  int e = e0;
  if ((e & 1) && e < e1) { gs += w_in[csr_src[e]]; ++e; }
  for (; e + 8 <= e1; e += 8) {
    uint2 p0 = *(const uint2*)(csr_src + e);
    uint2 p1 = *(const uint2*)(csr_src + e + 2);
    uint2 p2 = *(const uint2*)(csr_src + e + 4);
    uint2 p3 = *(const uint2*)(csr_src + e + 6);
    float w0 = w_in[p0.x], w1 = w_in[p0.y], w2 = w_in[p1.x], w3 = w_in[p1.y];
    float w4 = w_in[p2.x], w5 = w_in[p2.y], w6 = w_in[p3.x], w7 = w_in[p3.y];
    gs += ((w0 + w1) + (w2 + w3)) + ((w4 + w5) + (w6 + w7));
  }
  for (; e < e1; ++e) gs += w_in[csr_src[e]];
  float s = gk[i] + dinv[i] * gs;
  w_out[i] = dinv[i] * s;
}

// ---------------- last Horner hop fused with combine + sel decode ----------------
__global__ void k_horner_fin(const float* __restrict__ g0, const float* __restrict__ w_in,
                             const float* __restrict__ x1, const int* __restrict__ y,
                             const unsigned char* __restrict__ selb, const int* __restrict__ selflag,
                             const float* __restrict__ Wlin, const float* __restrict__ blin,
                             const float* __restrict__ bt3,
                             const int* __restrict__ row_start, const int* __restrict__ csr_src,
                             const float* __restrict__ dinv, float* __restrict__ out) {
  int i = blockIdx.x * 256 + threadIdx.x;
  int e0 = row_start[i], e1 = row_start[i + 1];
  float gs = 0.0f;
  int e = e0;
  if ((e & 1) && e < e1) { gs += w_in[csr_src[e]]; ++e; }
  for (; e + 8 <= e1; e += 8) {
    uint2 p0 = *(const uint2*)(csr_src + e);
    uint2 p1 = *(const uint2*)(csr_src + e + 2);
    uint2 p2 = *(const uint2*)(csr_src + e + 4);
    uint2 p3 = *(const uint2*)(csr_src + e + 6);
    float w0 = w_in[p0.x], w1 = w_in[p0.y], w2 = w_in[p1.x], w3 = w_in[p1.y];
    float w4 = w_in[p2.x], w5 = w_in[p2.y], w6 = w_in[p3.x], w7 = w_in[p3.y];
    gs += ((w0 + w1) + (w2 + w3)) + ((w4 + w5) + (w6 + w7));
  }
  for (; e < e1; ++e) gs += w_in[csr_src[e]];
  float s = g0[i] + dinv[i] * gs;
  float x3 = fmaxf(s + bt3[0], 0.0f);
  float v = fmaxf(x1[i] * Wlin[0] + x3 * Wlin[1] + blin[0], 0.0f);
  bool selv = (*selflag) ? (selb[i] != 0) : (((const int*)selb)[i] != 0);
  bool z = selv && (y[i] == 0);
  out[i] = z ? 0.0f : v;
}

extern "C" void kernel_launch(void* const* d_in, const int* in_sizes, int n_in,
                              void* d_out, int out_size, void* d_ws, size_t ws_size,
                              hipStream_t stream) {
  const float* x    = (const float*)d_in[0];
  const int*   ei   = (const int*)d_in[1];
  const int*   y    = (const int*)d_in[2];
  const unsigned char* sel = (const unsigned char*)d_in[3];
  const float* Wl1  = (const float*)d_in[4];
  const float* Wr1  = (const float*)d_in[5];
  const float* b1   = (const float*)d_in[6];
  const float* Wl2  = (const float*)d_in[7];
  const float* Wr2  = (const float*)d_in[8];
  const float* b2   = (const float*)d_in[9];
  const float* Wl3  = (const float*)d_in[10];
  const float* Wr3  = (const float*)d_in[11];
  const float* b3   = (const float*)d_in[12];
  const float* Wt1  = (const float*)d_in[13];
  const float* bt1  = (const float*)d_in[14];
  const float* Wt2  = (const float*)d_in[15];
  const float* bt2  = (const float*)d_in[16];
  const float* Wt3  = (const float*)d_in[17];
  const float* bt3  = (const float*)d_in[18];
  const float* Wlin = (const float*)d_in[19];
  const float* blin = (const float*)d_in[20];

  const size_t MB = 1 << 20;
  unsigned char* w8 = (unsigned char*)d_ws;
  int*   deg       = (int*)(w8 + 0 * MB);
  int*   row_start = (int*)(w8 + 2 * MB);
  float* inv_deg   = (float*)(w8 + 4 * MB);
  float* dinv      = (float*)(w8 + 5 * MB);
  float* x1        = (float*)(w8 + 6 * MB);
  float* g_l       = (float*)(w8 + 7 * MB);
  float* g_r       = (float*)(w8 + 8 * MB);
  int*   btot      = (int*)(w8 + 9 * MB);
  int*   bbase     = (int*)(w8 + 9 * MB + 4096);
  int*   selflag   = (int*)(w8 + 9 * MB + 8192);
  float* w6a       = (float*)(w8 + 11 * MB);
  float* w6b       = (float*)(w8 + 12 * MB);
  ushort_t* Wtc    = (ushort_t*)(w8 + 14 * MB);   // 64 KB
  ushort_t* Wc1    = (ushort_t*)(w8 + 15 * MB);   // 8 KB
  int*   csr_src   = (int*)(w8 + 16 * MB);        // 8 MiB
  int*   pos       = (int*)(w8 + 24 * MB);        // 8 MiB
  ushort_t* xpb    = (ushort_t*)(w8 + 40 * MB);   // 8 MiB
  ushort_t* H      = (ushort_t*)(w8 + 48 * MB);   // 64 MiB
  ushort_t* AGG    = (ushort_t*)(w8 + 112 * MB);  // 64 MiB -> peak 176 MiB
  ushort_t* xc     = (ushort_t*)(w8 + 112 * MB);  // 16 MiB overlay (dead before prop128)
  // TAG overlays (AGG region dead after SAGE)
  ushort_t* T0  = (ushort_t*)(w8 + 112 * MB);
  ushort_t* T1  = (ushort_t*)(w8 + 120 * MB);
  ushort_t* wA  = (ushort_t*)(w8 + 128 * MB);
  ushort_t* wB  = (ushort_t*)(w8 + 136 * MB);
  float* gT     = (float*)(w8 + 144 * MB);        // 15 x N fp32

  // ---- sel probe ----
  k_selprobe<<<1, 256, 0, stream>>>(sel, selflag);

  // ---- graph preprocessing ----
  hipMemsetAsync(deg, 0, MB, stream);
  k_deg<<<EE / 256, 256, 0, stream>>>(ei, deg, pos);
  k_scan_partial<<<256, 256, 0, stream>>>(deg, btot);
  k_scan_block<<<1, 256, 0, stream>>>(btot, bbase, row_start);
  k_scan_final<<<256, 256, 0, stream>>>(deg, bbase, row_start, inv_deg, dinv);
  k_fill<<<EE / 256, 256, 0, stream>>>(ei, row_start, pos, csr_src);
  k_pad_x<<<NN * 16 / 256, 256, 0, stream>>>(x, xpb, xc);
  k_convW<<<128, 256, 0, stream>>>(Wl2, Wr2, Wtc);
  k_convW1<<<16, 256, 0, stream>>>(Wl1, Wr1, Wc1);

  // ---- SAGE branch ----
  k_prop16b<<<NN * 2 / 256, 256, 0, stream>>>(xpb, xc, row_start, csr_src, inv_deg);
  k_gemm_small_mfma<<<NN / 64, 256, 0, stream>>>(xc, Wc1, b1, H);
  for (int l = 0; l < 4; ++l) {
    k_prop128<<<NN / 4, 256, 0, stream>>>(H, AGG, row_start, csr_src, inv_deg);
    k_gemm128_mfma<<<NN / 256, 512, 0, stream>>>(AGG, H, Wtc, b2, H);
  }
  k_wide_to1<<<NN / 4, 256, 0, stream>>>(H, Wl3, Wr3, g_l, g_r);
  k_sage_final<<<NN / 256, 256, 0, stream>>>(g_l, g_r, b3, row_start, csr_src, inv_deg, x1);

  // ---- TAG branch ----
  const size_t FT = (size_t)FIN * TW;
  const size_t TT = (size_t)TW * TW;
  const int TG = NN * 2 / 256;
  ushort_t* wi = wA; ushort_t* wo = wB;
  k_tag_hh<0><<<TG, 256, 0, stream>>>(xpb, Wt1 + 15 * FT, FIN, nullptr, wi, nullptr,
                                      nullptr, 0, nullptr, row_start, csr_src, dinv);
  for (int k = 14; k >= 1; --k) {
    k_tag_hh<1><<<TG, 256, 0, stream>>>(xpb, Wt1 + (size_t)k * FT, FIN, wi, wo, nullptr,
                                        nullptr, 0, nullptr, row_start, csr_src, dinv);
    ushort_t* tmp = wi; wi = wo; wo = tmp;
  }
  k_tag_hh<3><<<TG, 256, 0, stream>>>(xpb, Wt1, FIN, wi, T0, bt1,
                                      Wt2 + 15 * TT, TW, wo, row_start, csr_src, dinv);
  { ushort_t* tmp = wi; wi = wo; wo = tmp; }
  ushort_t* tin = T0; ushort_t* tout = T1;
  for (int l = 0; l < 4; ++l) {
    for (int k = 14; k >= 1; --k) {
      k_tag_hh<1><<<TG, 256, 0, stream>>>(tin, Wt2 + (size_t)k * TT, TW, wi, wo, nullptr,
                                          nullptr, 0, nullptr, row_start, csr_src, dinv);
      ushort_t* tmp = wi; wi = wo; wo = tmp;
    }
    if (l < 3) {
      k_tag_hh<3><<<TG, 256, 0, stream>>>(tin, Wt2, TW, wi, tout, bt2,
                                          Wt2 + 15 * TT, TW, wo, row_start, csr_src, dinv);
      ushort_t* tmp = wi; wi = wo; wo = tmp;
    } else {
      k_tag_hh<2><<<TG, 256, 0, stream>>>(tin, Wt2, TW, wi, tout, bt2,
                                          nullptr, 0, nullptr, row_start, csr_src, dinv);
    }
    ushort_t* tmp = tin; tin = tout; tout = tmp;
  }
  // layer 6
  k_tag_g<<<NN / 256, 256, 0, stream>>>(tin, Wt3, dinv, gT, w6a);
  float* fwi = w6a; float* fwo = w6b;
  for (int k = 14; k >= 1; --k) {
    k_horner<<<NN / 256, 256, 0, stream>>>(gT + (size_t)k * NN, fwi, fwo,
                                           row_start, csr_src, dinv);
    float* tmp = fwi; fwi = fwo; fwo = tmp;
  }
  k_horner_fin<<<NN / 256, 256, 0, stream>>>(gT, fwi, x1, y, sel, selflag, Wlin, blin, bt3,
                                             row_start, csr_src, dinv, (float*)d_out);
}